// Round 12
// baseline (497.740 us; speedup 1.0000x reference)
//
// Round 12: revert edgew/wbuf (round-11 regression: cost > savings).
// GEMMs rewritten LDS-free: W is L2-resident + wave-broadcast loads;
// 4x4 per-thread tile, __launch_bounds__(256,8) -> VGPR<=64 -> up to 8 waves/SIMD.
// Agg kernels = round-10 proven (fp16 h, 8x unroll, inline exp).
#include <hip/hip_runtime.h>
#include <hip/hip_fp16.h>

#define NNODES 100000
#define NEDGES 1600000
#define INDIM 128
#define HID 32
#define HEADS 4
#define OUTDIM 64
#define NEG_SLOPE 0.2f
#define NRANGES 8
#define RSIZE (NNODES / NRANGES)

__device__ __forceinline__ float lrelu(float x) { return x > 0.f ? x : NEG_SLOPE * x; }

// ---------------- CSR build (dst-sorted) ----------------
__global__ void k_degree(const int* __restrict__ dst, int* __restrict__ deg, int E) {
    int i = blockIdx.x * blockDim.x + threadIdx.x;
    if (i < E) atomicAdd(&deg[dst[i]], 1);
}

__global__ void k_scanA(const int* __restrict__ deg, int* __restrict__ rowptr,
                        int* __restrict__ bsum, int N) {
    __shared__ int ls[1024];
    int t = threadIdx.x;
    int i = blockIdx.x * 1024 + t;
    int v = (i < N) ? deg[i] : 0;
    ls[t] = v;
    __syncthreads();
    for (int off = 1; off < 1024; off <<= 1) {
        int add = (t >= off) ? ls[t - off] : 0;
        __syncthreads();
        ls[t] += add;
        __syncthreads();
    }
    int incl = ls[t];
    if (i < N) rowptr[i] = incl - v;
    if (t == 1023) bsum[blockIdx.x] = incl;
}

__global__ void k_scanB(const int* __restrict__ bsum, int* __restrict__ boff, int nb) {
    __shared__ int ls[128];
    int t = threadIdx.x;
    int v = (t < nb) ? bsum[t] : 0;
    ls[t] = v;
    __syncthreads();
    for (int off = 1; off < 128; off <<= 1) {
        int add = (t >= off) ? ls[t - off] : 0;
        __syncthreads();
        ls[t] += add;
        __syncthreads();
    }
    if (t < nb) boff[t] = ls[t] - v;
}

__global__ void k_scanC(int* __restrict__ rowptr, int* __restrict__ cursor,
                        const int* __restrict__ boff, int N, int E) {
    int t = threadIdx.x;
    int i = blockIdx.x * 1024 + t;
    if (i < N) {
        int r = rowptr[i] + boff[blockIdx.x];
        rowptr[i] = r;
        cursor[i] = r;
    }
    if (blockIdx.x == 0 && t == 0) rowptr[N] = E;
}

// dst-range-partitioned, XCD-affine fill (round-10, proven)
__global__ __launch_bounds__(256) void k_fill(const int* __restrict__ src,
                                              const int* __restrict__ dst,
                                              int* __restrict__ cursor,
                                              int* __restrict__ csr_src, int E) {
    int range = blockIdx.x & (NRANGES - 1);
    int chunk = blockIdx.x >> 3;
    int nchunks = gridDim.x >> 3;
    int lo = range * RSIZE;
    int hi = (range == NRANGES - 1) ? NNODES : lo + RSIZE;
    int per = (E + nchunks - 1) / nchunks;
    int beg = chunk * per;
    int end = min(E, beg + per);
    for (int i = beg + threadIdx.x; i < end; i += 256) {
        int d = dst[i];
        if (d >= lo && d < hi) {
            int slot = atomicAdd(&cursor[d], 1);
            csr_src[slot] = src[i];
        }
    }
}

// ---------------- GEMM 1: h1h[N,128](fp16) = x @ W1 — LDS-free, 4x4 tile ----------------
__global__ __launch_bounds__(256, 8) void k_gemm1(const float* __restrict__ x,
                                                  const float* __restrict__ W,
                                                  __half* __restrict__ h) {
    int t = threadIdx.x;
    int cg = t & 31;       // 32 col groups x 4 cols = 128 cols
    int rg = t >> 5;       // 8 row groups x 4 rows = 32 rows/block
    int r0 = blockIdx.x * 32 + rg * 4;
    const float4* x4 = (const float4*)x;
    const float4* W4 = (const float4*)W;

    int ridx[4];
    #pragma unroll
    for (int rr = 0; rr < 4; ++rr) {
        int r = r0 + rr;
        ridx[rr] = r < NNODES ? r : NNODES - 1;
    }
    float4 acc[4];
    #pragma unroll
    for (int rr = 0; rr < 4; ++rr) acc[rr] = make_float4(0.f, 0.f, 0.f, 0.f);

    for (int k = 0; k < INDIM; k += 4) {
        float4 wv0 = W4[(k + 0) * 32 + cg];   // L2-resident, wave-broadcast
        float4 wv1 = W4[(k + 1) * 32 + cg];
        float4 wv2 = W4[(k + 2) * 32 + cg];
        float4 wv3 = W4[(k + 3) * 32 + cg];
        #pragma unroll
        for (int rr = 0; rr < 4; ++rr) {
            float4 xv = x4[(size_t)ridx[rr] * 32 + (k >> 2)];
            acc[rr].x = fmaf(xv.x, wv0.x, fmaf(xv.y, wv1.x, fmaf(xv.z, wv2.x, fmaf(xv.w, wv3.x, acc[rr].x))));
            acc[rr].y = fmaf(xv.x, wv0.y, fmaf(xv.y, wv1.y, fmaf(xv.z, wv2.y, fmaf(xv.w, wv3.y, acc[rr].y))));
            acc[rr].z = fmaf(xv.x, wv0.z, fmaf(xv.y, wv1.z, fmaf(xv.z, wv2.z, fmaf(xv.w, wv3.z, acc[rr].z))));
            acc[rr].w = fmaf(xv.x, wv0.w, fmaf(xv.y, wv1.w, fmaf(xv.z, wv2.w, fmaf(xv.w, wv3.w, acc[rr].w))));
        }
    }
    #pragma unroll
    for (int rr = 0; rr < 4; ++rr) {
        int r = r0 + rr;
        if (r < NNODES) {
            union { __half2 h2[2]; uint2 u; } pk;
            pk.h2[0] = __floats2half2_rn(acc[rr].x, acc[rr].y);
            pk.h2[1] = __floats2half2_rn(acc[rr].z, acc[rr].w);
            ((uint2*)h)[(size_t)r * 32 + cg] = pk.u;
        }
    }
}

// ---------------- GEMM 2: h2h[N,64](fp16) = eluh @ W2 — LDS-free, 4x4 tile ----------------
__global__ __launch_bounds__(256, 8) void k_gemm2(const float* __restrict__ x,
                                                  const float* __restrict__ W,
                                                  __half* __restrict__ h) {
    int t = threadIdx.x;
    int cg = t & 15;       // 16 col groups x 4 = 64 cols
    int rg = t >> 4;       // 16 row groups x 4 rows = 64 rows/block
    int r0 = blockIdx.x * 64 + rg * 4;
    const float4* x4 = (const float4*)x;
    const float4* W4 = (const float4*)W;

    int ridx[4];
    #pragma unroll
    for (int rr = 0; rr < 4; ++rr) {
        int r = r0 + rr;
        ridx[rr] = r < NNODES ? r : NNODES - 1;
    }
    float4 acc[4];
    #pragma unroll
    for (int rr = 0; rr < 4; ++rr) acc[rr] = make_float4(0.f, 0.f, 0.f, 0.f);

    for (int k = 0; k < 128; k += 4) {
        float4 wv0 = W4[(k + 0) * 16 + cg];
        float4 wv1 = W4[(k + 1) * 16 + cg];
        float4 wv2 = W4[(k + 2) * 16 + cg];
        float4 wv3 = W4[(k + 3) * 16 + cg];
        #pragma unroll
        for (int rr = 0; rr < 4; ++rr) {
            float4 xv = x4[(size_t)ridx[rr] * 32 + (k >> 2)];
            acc[rr].x = fmaf(xv.x, wv0.x, fmaf(xv.y, wv1.x, fmaf(xv.z, wv2.x, fmaf(xv.w, wv3.x, acc[rr].x))));
            acc[rr].y = fmaf(xv.x, wv0.y, fmaf(xv.y, wv1.y, fmaf(xv.z, wv2.y, fmaf(xv.w, wv3.y, acc[rr].y))));
            acc[rr].z = fmaf(xv.x, wv0.z, fmaf(xv.y, wv1.z, fmaf(xv.z, wv2.z, fmaf(xv.w, wv3.z, acc[rr].z))));
            acc[rr].w = fmaf(xv.x, wv0.w, fmaf(xv.y, wv1.w, fmaf(xv.z, wv2.w, fmaf(xv.w, wv3.w, acc[rr].w))));
        }
    }
    #pragma unroll
    for (int rr = 0; rr < 4; ++rr) {
        int r = r0 + rr;
        if (r < NNODES) {
            union { __half2 h2[2]; uint2 u; } pk;
            pk.h2[0] = __floats2half2_rn(acc[rr].x, acc[rr].y);
            pk.h2[1] = __floats2half2_rn(acc[rr].z, acc[rr].w);
            ((uint2*)h)[(size_t)r * 16 + cg] = pk.u;
        }
    }
}

// ---------------- alpha kernels (round-9/10, proven) ----------------
__global__ void k_alpha1(const __half* __restrict__ h, const float* __restrict__ a_src,
                         const float* __restrict__ a_dst, float* __restrict__ asrc,
                         float* __restrict__ adst) {
    int t = threadIdx.x;
    int n = blockIdx.x * 4 + (t >> 6);
    if (n >= NNODES) return;
    int l = t & 63;
    int c0 = 2 * l;
    int head = l >> 4;
    float2 hv = __half22float2(((const __half2*)h)[(size_t)n * 64 + l]);
    int wi = head * HID + (c0 & 31);
    float ps = hv.x * a_src[wi] + hv.y * a_src[wi + 1];
    float pd = hv.x * a_dst[wi] + hv.y * a_dst[wi + 1];
    #pragma unroll
    for (int off = 1; off < 16; off <<= 1) {
        ps += __shfl_xor(ps, off, 16);
        pd += __shfl_xor(pd, off, 16);
    }
    if ((l & 15) == 0) {
        asrc[n * 4 + head] = ps;
        adst[n * 4 + head] = pd;
    }
}

__global__ void k_alpha2(const __half* __restrict__ h, const float* __restrict__ a_src,
                         const float* __restrict__ a_dst, float* __restrict__ asrc,
                         float* __restrict__ adst) {
    int t = threadIdx.x;
    int n = blockIdx.x * 4 + (t >> 6);
    if (n >= NNODES) return;
    int l = t & 63;
    float hv = __half2float(h[(size_t)n * 64 + l]);
    float ps = hv * a_src[l];
    float pd = hv * a_dst[l];
    #pragma unroll
    for (int off = 1; off < 64; off <<= 1) {
        ps += __shfl_xor(ps, off, 64);
        pd += __shfl_xor(pd, off, 64);
    }
    if (l == 0) {
        asrc[n] = ps;
        adst[n] = pd;
    }
}

// ---------------- aggregation layer 1 (round-10, proven): fp16 gathers, 8x unroll ----------------
__global__ __launch_bounds__(256) void k_agg1(const __half* __restrict__ h,
                                              const float* __restrict__ asrc,
                                              const float* __restrict__ adst,
                                              const int* __restrict__ rowptr,
                                              const int* __restrict__ csr_src,
                                              const float* __restrict__ b,
                                              float* __restrict__ out) {
    int t = threadIdx.x;
    int n = blockIdx.x * 4 + (t >> 6);
    if (n >= NNODES) return;
    int l = t & 63;
    int head = l >> 4;
    int c0 = 2 * l;
    const __half2* hh = (const __half2*)h;

    float adsth = adst[n * 4 + head];
    float w = __expf(lrelu(asrc[n * 4 + head] + adsth));
    float2 hv = __half22float2(hh[(size_t)n * 64 + l]);
    float dsum = w;
    float a0 = w * hv.x;
    float a1 = w * hv.y;

    int beg = rowptr[n];
    int end = rowptr[n + 1];
    int p = beg;
    for (; p + 8 <= end; p += 8) {
        int s[8];
        #pragma unroll
        for (int j = 0; j < 8; ++j) s[j] = __builtin_amdgcn_readfirstlane(csr_src[p + j]);
        float ww[8];
        #pragma unroll
        for (int j = 0; j < 8; ++j) ww[j] = __expf(lrelu(asrc[(size_t)s[j] * 4 + head] + adsth));
        float2 hx[8];
        #pragma unroll
        for (int j = 0; j < 8; ++j) hx[j] = __half22float2(hh[(size_t)s[j] * 64 + l]);
        #pragma unroll
        for (int j = 0; j < 8; ++j) {
            dsum += ww[j];
            a0 = fmaf(ww[j], hx[j].x, a0);
            a1 = fmaf(ww[j], hx[j].y, a1);
        }
    }
    for (; p < end; ++p) {
        int s = __builtin_amdgcn_readfirstlane(csr_src[p]);
        float ws = __expf(lrelu(asrc[(size_t)s * 4 + head] + adsth));
        float2 hs = __half22float2(hh[(size_t)s * 64 + l]);
        dsum += ws;
        a0 = fmaf(ws, hs.x, a0);
        a1 = fmaf(ws, hs.y, a1);
    }
    float inv = 1.0f / dsum;
    float r0 = a0 * inv + b[c0];
    float r1 = a1 * inv + b[c0 + 1];
    r0 = r0 > 0.f ? r0 : __expf(r0) - 1.f;
    r1 = r1 > 0.f ? r1 : __expf(r1) - 1.f;
    *(float2*)&out[(size_t)n * 128 + c0] = make_float2(r0, r1);
}

// ---------------- aggregation layer 2 (round-10, proven) ----------------
__global__ __launch_bounds__(256) void k_agg2(const __half* __restrict__ h,
                                              const float* __restrict__ asrc,
                                              const float* __restrict__ adst,
                                              const int* __restrict__ rowptr,
                                              const int* __restrict__ csr_src,
                                              const float* __restrict__ b,
                                              float* __restrict__ out) {
    int t = threadIdx.x;
    int n = blockIdx.x * 4 + (t >> 6);
    if (n >= NNODES) return;
    int l = t & 63;

    float adv = adst[n];
    float w = __expf(lrelu(asrc[n] + adv));
    float dsum = w;
    float acc = w * __half2float(h[(size_t)n * 64 + l]);

    int beg = rowptr[n];
    int end = rowptr[n + 1];
    int p = beg;
    for (; p + 8 <= end; p += 8) {
        int s[8];
        #pragma unroll
        for (int j = 0; j < 8; ++j) s[j] = __builtin_amdgcn_readfirstlane(csr_src[p + j]);
        float ww[8];
        #pragma unroll
        for (int j = 0; j < 8; ++j) ww[j] = __expf(lrelu(asrc[s[j]] + adv));
        float hx[8];
        #pragma unroll
        for (int j = 0; j < 8; ++j) hx[j] = __half2float(h[(size_t)s[j] * 64 + l]);
        #pragma unroll
        for (int j = 0; j < 8; ++j) {
            dsum += ww[j];
            acc = fmaf(ww[j], hx[j], acc);
        }
    }
    for (; p < end; ++p) {
        int s = __builtin_amdgcn_readfirstlane(csr_src[p]);
        float ws = __expf(lrelu(asrc[s] + adv));
        acc = fmaf(ws, __half2float(h[(size_t)s * 64 + l]), acc);
        dsum += ws;
    }
    out[(size_t)n * 64 + l] = acc / dsum + b[l];
}

extern "C" void kernel_launch(void* const* d_in, const int* in_sizes, int n_in,
                              void* d_out, int out_size, void* d_ws, size_t ws_size,
                              hipStream_t stream) {
    const float* x      = (const float*)d_in[0];
    const int*   ei     = (const int*)d_in[1];
    const float* W1     = (const float*)d_in[2];
    const float* a_src1 = (const float*)d_in[3];
    const float* a_dst1 = (const float*)d_in[4];
    const float* b1     = (const float*)d_in[5];
    const float* W2     = (const float*)d_in[6];
    const float* a_src2 = (const float*)d_in[7];
    const float* a_dst2 = (const float*)d_in[8];
    const float* b2     = (const float*)d_in[9];
    float* out = (float*)d_out;

    const int* src = ei;
    const int* dst = ei + NEDGES;

    char* ws = (char*)d_ws;
    size_t off = 0;
    auto alloc = [&](size_t bytes) {
        void* p = ws + off;
        off += (bytes + 255) & ~255ull;
        return p;
    };
    int* rowptr   = (int*)alloc((NNODES + 1) * sizeof(int));
    int* cursor   = (int*)alloc(NNODES * sizeof(int));
    int* csr_src  = (int*)alloc((size_t)NEDGES * sizeof(int));
    __half* h1h   = (__half*)alloc((size_t)NNODES * 128 * sizeof(__half)); // 25.6MB; layer-2 h overlays
    float* eluh   = (float*)alloc((size_t)NNODES * 128 * sizeof(float));   // 51.2MB
    float* asrc1  = (float*)alloc((size_t)NNODES * 4 * sizeof(float));
    float* adst1  = (float*)alloc((size_t)NNODES * 4 * sizeof(float));
    int* bsum     = (int*)alloc(128 * sizeof(int));
    int* boff     = (int*)alloc(129 * sizeof(int));

    int nb = (NNODES + 1023) / 1024;  // 98

    hipMemsetAsync(cursor, 0, NNODES * sizeof(int), stream);
    k_degree<<<(NEDGES + 255) / 256, 256, 0, stream>>>(dst, cursor, NEDGES);
    k_scanA<<<nb, 1024, 0, stream>>>(cursor, rowptr, bsum, NNODES);
    k_scanB<<<1, 128, 0, stream>>>(bsum, boff, nb);
    k_scanC<<<nb, 1024, 0, stream>>>(rowptr, cursor, boff, NNODES, NEDGES);
    k_fill<<<NRANGES * 200, 256, 0, stream>>>(src, dst, cursor, csr_src, NEDGES);

    int gn = (NNODES + 3) / 4;

    // layer 1
    k_gemm1<<<(NNODES + 31) / 32, 256, 0, stream>>>(x, W1, h1h);
    k_alpha1<<<gn, 256, 0, stream>>>(h1h, a_src1, a_dst1, asrc1, adst1);
    k_agg1<<<gn, 256, 0, stream>>>(h1h, asrc1, adst1, rowptr, csr_src, b1, eluh);

    // layer 2 (h overlays h1h; asrc/adst reused)
    k_gemm2<<<(NNODES + 63) / 64, 256, 0, stream>>>(eluh, W2, h1h);
    k_alpha2<<<gn, 256, 0, stream>>>(h1h, a_src2, a_dst2, asrc1, adst1);
    k_agg2<<<gn, 256, 0, stream>>>(h1h, asrc1, adst1, rowptr, csr_src, b2, out);
}

// Round 13
// 394.792 us; speedup vs baseline: 1.2608x; 1.2608x over previous
//
// Round 13: MFMA GEMMs (fp16 in, fp32 acc) — v_mfma_f32_16x16x32_f16.
// W pre-transposed to fp16 WT[n][k] so B-fragments are contiguous 16B loads;
// A-fragments converted fp32->fp16 in-register (gemm1) or loaded fp16 (gemm2,
// eluh now stored fp16 by agg1). C/D layout col=lane&15,row=(lane>>4)*4+reg
// (HW-verified per guide). Everything else = round-10 proven (437us).
#include <hip/hip_runtime.h>
#include <hip/hip_fp16.h>

#define NNODES 100000
#define NEDGES 1600000
#define INDIM 128
#define HID 32
#define HEADS 4
#define OUTDIM 64
#define NEG_SLOPE 0.2f
#define NRANGES 8
#define RSIZE (NNODES / NRANGES)

typedef _Float16 half8 __attribute__((ext_vector_type(8)));
typedef float floatx4 __attribute__((ext_vector_type(4)));

__device__ __forceinline__ float lrelu(float x) { return x > 0.f ? x : NEG_SLOPE * x; }

// ---------------- CSR build (dst-sorted) ----------------
__global__ void k_degree(const int* __restrict__ dst, int* __restrict__ deg, int E) {
    int i = blockIdx.x * blockDim.x + threadIdx.x;
    if (i < E) atomicAdd(&deg[dst[i]], 1);
}

__global__ void k_scanA(const int* __restrict__ deg, int* __restrict__ rowptr,
                        int* __restrict__ bsum, int N) {
    __shared__ int ls[1024];
    int t = threadIdx.x;
    int i = blockIdx.x * 1024 + t;
    int v = (i < N) ? deg[i] : 0;
    ls[t] = v;
    __syncthreads();
    for (int off = 1; off < 1024; off <<= 1) {
        int add = (t >= off) ? ls[t - off] : 0;
        __syncthreads();
        ls[t] += add;
        __syncthreads();
    }
    int incl = ls[t];
    if (i < N) rowptr[i] = incl - v;
    if (t == 1023) bsum[blockIdx.x] = incl;
}

__global__ void k_scanB(const int* __restrict__ bsum, int* __restrict__ boff, int nb) {
    __shared__ int ls[128];
    int t = threadIdx.x;
    int v = (t < nb) ? bsum[t] : 0;
    ls[t] = v;
    __syncthreads();
    for (int off = 1; off < 128; off <<= 1) {
        int add = (t >= off) ? ls[t - off] : 0;
        __syncthreads();
        ls[t] += add;
        __syncthreads();
    }
    if (t < nb) boff[t] = ls[t] - v;
}

__global__ void k_scanC(int* __restrict__ rowptr, int* __restrict__ cursor,
                        const int* __restrict__ boff, int N, int E) {
    int t = threadIdx.x;
    int i = blockIdx.x * 1024 + t;
    if (i < N) {
        int r = rowptr[i] + boff[blockIdx.x];
        rowptr[i] = r;
        cursor[i] = r;
    }
    if (blockIdx.x == 0 && t == 0) rowptr[N] = E;
}

// dst-range-partitioned, XCD-affine fill (round-10, proven)
__global__ __launch_bounds__(256) void k_fill(const int* __restrict__ src,
                                              const int* __restrict__ dst,
                                              int* __restrict__ cursor,
                                              int* __restrict__ csr_src, int E) {
    int range = blockIdx.x & (NRANGES - 1);
    int chunk = blockIdx.x >> 3;
    int nchunks = gridDim.x >> 3;
    int lo = range * RSIZE;
    int hi = (range == NRANGES - 1) ? NNODES : lo + RSIZE;
    int per = (E + nchunks - 1) / nchunks;
    int beg = chunk * per;
    int end = min(E, beg + per);
    for (int i = beg + threadIdx.x; i < end; i += 256) {
        int d = dst[i];
        if (d >= lo && d < hi) {
            int slot = atomicAdd(&cursor[d], 1);
            csr_src[slot] = src[i];
        }
    }
}

// ---------------- weight transposes to fp16 ----------------
__global__ void k_cvtW1(const float* __restrict__ W, __half* __restrict__ WT) {
    int i = blockIdx.x * 256 + threadIdx.x;  // 16384 = 128n x 128k
    if (i < 128 * 128) {
        int n = i >> 7, k = i & 127;
        WT[i] = __float2half(W[k * 128 + n]);
    }
}
__global__ void k_cvtW2(const float* __restrict__ W, __half* __restrict__ WT) {
    int i = blockIdx.x * 256 + threadIdx.x;  // 8192 = 64n x 128k
    if (i < 64 * 128) {
        int n = i >> 7, k = i & 127;
        WT[i] = __float2half(W[k * 64 + n]);
    }
}

// ---------------- GEMM 1 (MFMA): h1h[N,128] = fp16(x) @ fp16(W1), fp32 acc ----------------
__global__ __launch_bounds__(256) void k_gemm1(const float* __restrict__ x,
                                               const __half* __restrict__ WT,  // [128n][128k]
                                               __half* __restrict__ h) {
    int t = threadIdx.x;
    int wid = t >> 6;
    int l = t & 63;
    int lm = l & 15;
    int lk = (l >> 4) * 8;
    int r0 = blockIdx.x * 64 + wid * 16;

    int row = r0 + lm;
    if (row >= NNODES) row = NNODES - 1;
    const float* xrow = x + (size_t)row * 128;

    half8 a[4];
    #pragma unroll
    for (int ks = 0; ks < 4; ++ks) {
        float4 u = *(const float4*)&xrow[ks * 32 + lk];
        float4 v = *(const float4*)&xrow[ks * 32 + lk + 4];
        half8 a8;
        a8[0] = (_Float16)u.x; a8[1] = (_Float16)u.y; a8[2] = (_Float16)u.z; a8[3] = (_Float16)u.w;
        a8[4] = (_Float16)v.x; a8[5] = (_Float16)v.y; a8[6] = (_Float16)v.z; a8[7] = (_Float16)v.w;
        a[ks] = a8;
    }
    const _Float16* WTh = (const _Float16*)WT;
    int rbase = r0 + (l >> 4) * 4;
    #pragma unroll
    for (int ct = 0; ct < 8; ++ct) {
        int col = ct * 16 + lm;
        floatx4 acc = {0.f, 0.f, 0.f, 0.f};
        #pragma unroll
        for (int ks = 0; ks < 4; ++ks) {
            half8 b = *(const half8*)&WTh[(size_t)col * 128 + ks * 32 + lk];
            acc = __builtin_amdgcn_mfma_f32_16x16x32_f16(a[ks], b, acc, 0, 0, 0);
        }
        #pragma unroll
        for (int reg = 0; reg < 4; ++reg) {
            int ro = rbase + reg;
            if (ro < NNODES) h[(size_t)ro * 128 + col] = __float2half(acc[reg]);
        }
    }
}

// ---------------- GEMM 2 (MFMA): h2h[N,64] = eluh(fp16) @ fp16(W2) ----------------
__global__ __launch_bounds__(256) void k_gemm2(const __half* __restrict__ eh,  // [N][128] fp16
                                               const __half* __restrict__ WT,  // [64n][128k]
                                               __half* __restrict__ h) {
    int t = threadIdx.x;
    int wid = t >> 6;
    int l = t & 63;
    int lm = l & 15;
    int lk = (l >> 4) * 8;
    int r0 = blockIdx.x * 64 + wid * 16;

    int row = r0 + lm;
    if (row >= NNODES) row = NNODES - 1;
    const _Float16* erow = (const _Float16*)eh + (size_t)row * 128;

    half8 a[4];
    #pragma unroll
    for (int ks = 0; ks < 4; ++ks) a[ks] = *(const half8*)&erow[ks * 32 + lk];

    const _Float16* WTh = (const _Float16*)WT;
    int rbase = r0 + (l >> 4) * 4;
    #pragma unroll
    for (int ct = 0; ct < 4; ++ct) {
        int col = ct * 16 + lm;
        floatx4 acc = {0.f, 0.f, 0.f, 0.f};
        #pragma unroll
        for (int ks = 0; ks < 4; ++ks) {
            half8 b = *(const half8*)&WTh[(size_t)col * 128 + ks * 32 + lk];
            acc = __builtin_amdgcn_mfma_f32_16x16x32_f16(a[ks], b, acc, 0, 0, 0);
        }
        #pragma unroll
        for (int reg = 0; reg < 4; ++reg) {
            int ro = rbase + reg;
            if (ro < NNODES) h[(size_t)ro * 64 + col] = __float2half(acc[reg]);
        }
    }
}

// ---------------- alpha kernels (proven) ----------------
__global__ void k_alpha1(const __half* __restrict__ h, const float* __restrict__ a_src,
                         const float* __restrict__ a_dst, float* __restrict__ asrc,
                         float* __restrict__ adst) {
    int t = threadIdx.x;
    int n = blockIdx.x * 4 + (t >> 6);
    if (n >= NNODES) return;
    int l = t & 63;
    int c0 = 2 * l;
    int head = l >> 4;
    float2 hv = __half22float2(((const __half2*)h)[(size_t)n * 64 + l]);
    int wi = head * HID + (c0 & 31);
    float ps = hv.x * a_src[wi] + hv.y * a_src[wi + 1];
    float pd = hv.x * a_dst[wi] + hv.y * a_dst[wi + 1];
    #pragma unroll
    for (int off = 1; off < 16; off <<= 1) {
        ps += __shfl_xor(ps, off, 16);
        pd += __shfl_xor(pd, off, 16);
    }
    if ((l & 15) == 0) {
        asrc[n * 4 + head] = ps;
        adst[n * 4 + head] = pd;
    }
}

__global__ void k_alpha2(const __half* __restrict__ h, const float* __restrict__ a_src,
                         const float* __restrict__ a_dst, float* __restrict__ asrc,
                         float* __restrict__ adst) {
    int t = threadIdx.x;
    int n = blockIdx.x * 4 + (t >> 6);
    if (n >= NNODES) return;
    int l = t & 63;
    float hv = __half2float(h[(size_t)n * 64 + l]);
    float ps = hv * a_src[l];
    float pd = hv * a_dst[l];
    #pragma unroll
    for (int off = 1; off < 64; off <<= 1) {
        ps += __shfl_xor(ps, off, 64);
        pd += __shfl_xor(pd, off, 64);
    }
    if (l == 0) {
        asrc[n] = ps;
        adst[n] = pd;
    }
}

// ---------------- aggregation layer 1 (round-10): fp16 gathers, 8x unroll; fp16 out ----------------
__global__ __launch_bounds__(256) void k_agg1(const __half* __restrict__ h,
                                              const float* __restrict__ asrc,
                                              const float* __restrict__ adst,
                                              const int* __restrict__ rowptr,
                                              const int* __restrict__ csr_src,
                                              const float* __restrict__ b,
                                              __half* __restrict__ out) {
    int t = threadIdx.x;
    int n = blockIdx.x * 4 + (t >> 6);
    if (n >= NNODES) return;
    int l = t & 63;
    int head = l >> 4;
    int c0 = 2 * l;
    const __half2* hh = (const __half2*)h;

    float adsth = adst[n * 4 + head];
    float w = __expf(lrelu(asrc[n * 4 + head] + adsth));
    float2 hv = __half22float2(hh[(size_t)n * 64 + l]);
    float dsum = w;
    float a0 = w * hv.x;
    float a1 = w * hv.y;

    int beg = rowptr[n];
    int end = rowptr[n + 1];
    int p = beg;
    for (; p + 8 <= end; p += 8) {
        int s[8];
        #pragma unroll
        for (int j = 0; j < 8; ++j) s[j] = __builtin_amdgcn_readfirstlane(csr_src[p + j]);
        float ww[8];
        #pragma unroll
        for (int j = 0; j < 8; ++j) ww[j] = __expf(lrelu(asrc[(size_t)s[j] * 4 + head] + adsth));
        float2 hx[8];
        #pragma unroll
        for (int j = 0; j < 8; ++j) hx[j] = __half22float2(hh[(size_t)s[j] * 64 + l]);
        #pragma unroll
        for (int j = 0; j < 8; ++j) {
            dsum += ww[j];
            a0 = fmaf(ww[j], hx[j].x, a0);
            a1 = fmaf(ww[j], hx[j].y, a1);
        }
    }
    for (; p < end; ++p) {
        int s = __builtin_amdgcn_readfirstlane(csr_src[p]);
        float ws = __expf(lrelu(asrc[(size_t)s * 4 + head] + adsth));
        float2 hs = __half22float2(hh[(size_t)s * 64 + l]);
        dsum += ws;
        a0 = fmaf(ws, hs.x, a0);
        a1 = fmaf(ws, hs.y, a1);
    }
    float inv = 1.0f / dsum;
    float r0 = a0 * inv + b[c0];
    float r1 = a1 * inv + b[c0 + 1];
    r0 = r0 > 0.f ? r0 : __expf(r0) - 1.f;
    r1 = r1 > 0.f ? r1 : __expf(r1) - 1.f;
    ((__half2*)out)[(size_t)n * 64 + l] = __floats2half2_rn(r0, r1);
}

// ---------------- aggregation layer 2 (round-10, proven) ----------------
__global__ __launch_bounds__(256) void k_agg2(const __half* __restrict__ h,
                                              const float* __restrict__ asrc,
                                              const float* __restrict__ adst,
                                              const int* __restrict__ rowptr,
                                              const int* __restrict__ csr_src,
                                              const float* __restrict__ b,
                                              float* __restrict__ out) {
    int t = threadIdx.x;
    int n = blockIdx.x * 4 + (t >> 6);
    if (n >= NNODES) return;
    int l = t & 63;

    float adv = adst[n];
    float w = __expf(lrelu(asrc[n] + adv));
    float dsum = w;
    float acc = w * __half2float(h[(size_t)n * 64 + l]);

    int beg = rowptr[n];
    int end = rowptr[n + 1];
    int p = beg;
    for (; p + 8 <= end; p += 8) {
        int s[8];
        #pragma unroll
        for (int j = 0; j < 8; ++j) s[j] = __builtin_amdgcn_readfirstlane(csr_src[p + j]);
        float ww[8];
        #pragma unroll
        for (int j = 0; j < 8; ++j) ww[j] = __expf(lrelu(asrc[s[j]] + adv));
        float hx[8];
        #pragma unroll
        for (int j = 0; j < 8; ++j) hx[j] = __half2float(h[(size_t)s[j] * 64 + l]);
        #pragma unroll
        for (int j = 0; j < 8; ++j) {
            dsum += ww[j];
            acc = fmaf(ww[j], hx[j], acc);
        }
    }
    for (; p < end; ++p) {
        int s = __builtin_amdgcn_readfirstlane(csr_src[p]);
        float ws = __expf(lrelu(asrc[s] + adv));
        acc = fmaf(ws, __half2float(h[(size_t)s * 64 + l]), acc);
        dsum += ws;
    }
    out[(size_t)n * 64 + l] = acc / dsum + b[l];
}

extern "C" void kernel_launch(void* const* d_in, const int* in_sizes, int n_in,
                              void* d_out, int out_size, void* d_ws, size_t ws_size,
                              hipStream_t stream) {
    const float* x      = (const float*)d_in[0];
    const int*   ei     = (const int*)d_in[1];
    const float* W1     = (const float*)d_in[2];
    const float* a_src1 = (const float*)d_in[3];
    const float* a_dst1 = (const float*)d_in[4];
    const float* b1     = (const float*)d_in[5];
    const float* W2     = (const float*)d_in[6];
    const float* a_src2 = (const float*)d_in[7];
    const float* a_dst2 = (const float*)d_in[8];
    const float* b2     = (const float*)d_in[9];
    float* out = (float*)d_out;

    const int* src = ei;
    const int* dst = ei + NEDGES;

    char* ws = (char*)d_ws;
    size_t off = 0;
    auto alloc = [&](size_t bytes) {
        void* p = ws + off;
        off += (bytes + 255) & ~255ull;
        return p;
    };
    int* rowptr   = (int*)alloc((NNODES + 1) * sizeof(int));
    int* cursor   = (int*)alloc(NNODES * sizeof(int));
    int* csr_src  = (int*)alloc((size_t)NEDGES * sizeof(int));
    __half* h1h   = (__half*)alloc((size_t)NNODES * 128 * sizeof(__half)); // 25.6MB; layer-2 h overlays
    __half* eluh  = (__half*)alloc((size_t)NNODES * 128 * sizeof(__half)); // 25.6MB fp16 now
    float* asrc1  = (float*)alloc((size_t)NNODES * 4 * sizeof(float));
    float* adst1  = (float*)alloc((size_t)NNODES * 4 * sizeof(float));
    __half* W1T   = (__half*)alloc(128 * 128 * sizeof(__half));
    __half* W2T   = (__half*)alloc(64 * 128 * sizeof(__half));
    int* bsum     = (int*)alloc(128 * sizeof(int));
    int* boff     = (int*)alloc(129 * sizeof(int));

    int nb = (NNODES + 1023) / 1024;  // 98

    hipMemsetAsync(cursor, 0, NNODES * sizeof(int), stream);
    k_cvtW1<<<64, 256, 0, stream>>>(W1, W1T);
    k_cvtW2<<<32, 256, 0, stream>>>(W2, W2T);
    k_degree<<<(NEDGES + 255) / 256, 256, 0, stream>>>(dst, cursor, NEDGES);
    k_scanA<<<nb, 1024, 0, stream>>>(cursor, rowptr, bsum, NNODES);
    k_scanB<<<1, 128, 0, stream>>>(bsum, boff, nb);
    k_scanC<<<nb, 1024, 0, stream>>>(rowptr, cursor, boff, NNODES, NEDGES);
    k_fill<<<NRANGES * 200, 256, 0, stream>>>(src, dst, cursor, csr_src, NEDGES);

    int gn = (NNODES + 3) / 4;
    int gb = (NNODES + 63) / 64;

    // layer 1
    k_gemm1<<<gb, 256, 0, stream>>>(x, W1T, h1h);
    k_alpha1<<<gn, 256, 0, stream>>>(h1h, a_src1, a_dst1, asrc1, adst1);
    k_agg1<<<gn, 256, 0, stream>>>(h1h, asrc1, adst1, rowptr, csr_src, b1, eluh);

    // layer 2 (h overlays h1h; asrc/adst reused)
    k_gemm2<<<gb, 256, 0, stream>>>(eluh, W2T, h1h);
    k_alpha2<<<gn, 256, 0, stream>>>(h1h, a_src2, a_dst2, asrc1, adst1);
    k_agg2<<<gn, 256, 0, stream>>>(h1h, asrc1, adst1, rowptr, csr_src, b2, out);
}

// Round 21
// 393.803 us; speedup vs baseline: 1.2639x; 1.0025x over previous
//
// Round 21: EXACT round-13 resubmission (proven 395us), sixth attempt.
// Rounds 16-20 all died host-side (disk-full writing ref_out.npz) before any
// compile/GPU work — pure infra failure, kernel source irrelevant. The
// session's best verified kernel stays queued until the pod heals.
#include <hip/hip_runtime.h>
#include <hip/hip_fp16.h>

#define NNODES 100000
#define NEDGES 1600000
#define INDIM 128
#define HID 32
#define HEADS 4
#define OUTDIM 64
#define NEG_SLOPE 0.2f
#define NRANGES 8
#define RSIZE (NNODES / NRANGES)

typedef _Float16 half8 __attribute__((ext_vector_type(8)));
typedef float floatx4 __attribute__((ext_vector_type(4)));

__device__ __forceinline__ float lrelu(float x) { return x > 0.f ? x : NEG_SLOPE * x; }

// ---------------- CSR build (dst-sorted) ----------------
__global__ void k_degree(const int* __restrict__ dst, int* __restrict__ deg, int E) {
    int i = blockIdx.x * blockDim.x + threadIdx.x;
    if (i < E) atomicAdd(&deg[dst[i]], 1);
}

__global__ void k_scanA(const int* __restrict__ deg, int* __restrict__ rowptr,
                        int* __restrict__ bsum, int N) {
    __shared__ int ls[1024];
    int t = threadIdx.x;
    int i = blockIdx.x * 1024 + t;
    int v = (i < N) ? deg[i] : 0;
    ls[t] = v;
    __syncthreads();
    for (int off = 1; off < 1024; off <<= 1) {
        int add = (t >= off) ? ls[t - off] : 0;
        __syncthreads();
        ls[t] += add;
        __syncthreads();
    }
    int incl = ls[t];
    if (i < N) rowptr[i] = incl - v;
    if (t == 1023) bsum[blockIdx.x] = incl;
}

__global__ void k_scanB(const int* __restrict__ bsum, int* __restrict__ boff, int nb) {
    __shared__ int ls[128];
    int t = threadIdx.x;
    int v = (t < nb) ? bsum[t] : 0;
    ls[t] = v;
    __syncthreads();
    for (int off = 1; off < 128; off <<= 1) {
        int add = (t >= off) ? ls[t - off] : 0;
        __syncthreads();
        ls[t] += add;
        __syncthreads();
    }
    if (t < nb) boff[t] = ls[t] - v;
}

__global__ void k_scanC(int* __restrict__ rowptr, int* __restrict__ cursor,
                        const int* __restrict__ boff, int N, int E) {
    int t = threadIdx.x;
    int i = blockIdx.x * 1024 + t;
    if (i < N) {
        int r = rowptr[i] + boff[blockIdx.x];
        rowptr[i] = r;
        cursor[i] = r;
    }
    if (blockIdx.x == 0 && t == 0) rowptr[N] = E;
}

// dst-range-partitioned, XCD-affine fill (round-10, proven)
__global__ __launch_bounds__(256) void k_fill(const int* __restrict__ src,
                                              const int* __restrict__ dst,
                                              int* __restrict__ cursor,
                                              int* __restrict__ csr_src, int E) {
    int range = blockIdx.x & (NRANGES - 1);
    int chunk = blockIdx.x >> 3;
    int nchunks = gridDim.x >> 3;
    int lo = range * RSIZE;
    int hi = (range == NRANGES - 1) ? NNODES : lo + RSIZE;
    int per = (E + nchunks - 1) / nchunks;
    int beg = chunk * per;
    int end = min(E, beg + per);
    for (int i = beg + threadIdx.x; i < end; i += 256) {
        int d = dst[i];
        if (d >= lo && d < hi) {
            int slot = atomicAdd(&cursor[d], 1);
            csr_src[slot] = src[i];
        }
    }
}

// ---------------- weight transposes to fp16 ----------------
__global__ void k_cvtW1(const float* __restrict__ W, __half* __restrict__ WT) {
    int i = blockIdx.x * 256 + threadIdx.x;
    if (i < 128 * 128) {
        int n = i >> 7, k = i & 127;
        WT[i] = __float2half(W[k * 128 + n]);
    }
}
__global__ void k_cvtW2(const float* __restrict__ W, __half* __restrict__ WT) {
    int i = blockIdx.x * 256 + threadIdx.x;
    if (i < 64 * 128) {
        int n = i >> 7, k = i & 127;
        WT[i] = __float2half(W[k * 64 + n]);
    }
}

// ---------------- GEMM 1 (MFMA): h1h[N,128] = fp16(x) @ fp16(W1), fp32 acc ----------------
__global__ __launch_bounds__(256) void k_gemm1(const float* __restrict__ x,
                                               const __half* __restrict__ WT,
                                               __half* __restrict__ h) {
    int t = threadIdx.x;
    int wid = t >> 6;
    int l = t & 63;
    int lm = l & 15;
    int lk = (l >> 4) * 8;
    int r0 = blockIdx.x * 64 + wid * 16;

    int row = r0 + lm;
    if (row >= NNODES) row = NNODES - 1;
    const float* xrow = x + (size_t)row * 128;

    half8 a[4];
    #pragma unroll
    for (int ks = 0; ks < 4; ++ks) {
        float4 u = *(const float4*)&xrow[ks * 32 + lk];
        float4 v = *(const float4*)&xrow[ks * 32 + lk + 4];
        half8 a8;
        a8[0] = (_Float16)u.x; a8[1] = (_Float16)u.y; a8[2] = (_Float16)u.z; a8[3] = (_Float16)u.w;
        a8[4] = (_Float16)v.x; a8[5] = (_Float16)v.y; a8[6] = (_Float16)v.z; a8[7] = (_Float16)v.w;
        a[ks] = a8;
    }
    const _Float16* WTh = (const _Float16*)WT;
    int rbase = r0 + (l >> 4) * 4;
    #pragma unroll
    for (int ct = 0; ct < 8; ++ct) {
        int col = ct * 16 + lm;
        floatx4 acc = {0.f, 0.f, 0.f, 0.f};
        #pragma unroll
        for (int ks = 0; ks < 4; ++ks) {
            half8 b = *(const half8*)&WTh[(size_t)col * 128 + ks * 32 + lk];
            acc = __builtin_amdgcn_mfma_f32_16x16x32_f16(a[ks], b, acc, 0, 0, 0);
        }
        #pragma unroll
        for (int reg = 0; reg < 4; ++reg) {
            int ro = rbase + reg;
            if (ro < NNODES) h[(size_t)ro * 128 + col] = __float2half(acc[reg]);
        }
    }
}

// ---------------- GEMM 2 (MFMA): h2h[N,64] = eluh(fp16) @ fp16(W2) ----------------
__global__ __launch_bounds__(256) void k_gemm2(const __half* __restrict__ eh,
                                               const __half* __restrict__ WT,
                                               __half* __restrict__ h) {
    int t = threadIdx.x;
    int wid = t >> 6;
    int l = t & 63;
    int lm = l & 15;
    int lk = (l >> 4) * 8;
    int r0 = blockIdx.x * 64 + wid * 16;

    int row = r0 + lm;
    if (row >= NNODES) row = NNODES - 1;
    const _Float16* erow = (const _Float16*)eh + (size_t)row * 128;

    half8 a[4];
    #pragma unroll
    for (int ks = 0; ks < 4; ++ks) a[ks] = *(const half8*)&erow[ks * 32 + lk];

    const _Float16* WTh = (const _Float16*)WT;
    int rbase = r0 + (l >> 4) * 4;
    #pragma unroll
    for (int ct = 0; ct < 4; ++ct) {
        int col = ct * 16 + lm;
        floatx4 acc = {0.f, 0.f, 0.f, 0.f};
        #pragma unroll
        for (int ks = 0; ks < 4; ++ks) {
            half8 b = *(const half8*)&WTh[(size_t)col * 128 + ks * 32 + lk];
            acc = __builtin_amdgcn_mfma_f32_16x16x32_f16(a[ks], b, acc, 0, 0, 0);
        }
        #pragma unroll
        for (int reg = 0; reg < 4; ++reg) {
            int ro = rbase + reg;
            if (ro < NNODES) h[(size_t)ro * 64 + col] = __float2half(acc[reg]);
        }
    }
}

// ---------------- alpha kernels (proven) ----------------
__global__ void k_alpha1(const __half* __restrict__ h, const float* __restrict__ a_src,
                         const float* __restrict__ a_dst, float* __restrict__ asrc,
                         float* __restrict__ adst) {
    int t = threadIdx.x;
    int n = blockIdx.x * 4 + (t >> 6);
    if (n >= NNODES) return;
    int l = t & 63;
    int c0 = 2 * l;
    int head = l >> 4;
    float2 hv = __half22float2(((const __half2*)h)[(size_t)n * 64 + l]);
    int wi = head * HID + (c0 & 31);
    float ps = hv.x * a_src[wi] + hv.y * a_src[wi + 1];
    float pd = hv.x * a_dst[wi] + hv.y * a_dst[wi + 1];
    #pragma unroll
    for (int off = 1; off < 16; off <<= 1) {
        ps += __shfl_xor(ps, off, 16);
        pd += __shfl_xor(pd, off, 16);
    }
    if ((l & 15) == 0) {
        asrc[n * 4 + head] = ps;
        adst[n * 4 + head] = pd;
    }
}

__global__ void k_alpha2(const __half* __restrict__ h, const float* __restrict__ a_src,
                         const float* __restrict__ a_dst, float* __restrict__ asrc,
                         float* __restrict__ adst) {
    int t = threadIdx.x;
    int n = blockIdx.x * 4 + (t >> 6);
    if (n >= NNODES) return;
    int l = t & 63;
    float hv = __half2float(h[(size_t)n * 64 + l]);
    float ps = hv * a_src[l];
    float pd = hv * a_dst[l];
    #pragma unroll
    for (int off = 1; off < 64; off <<= 1) {
        ps += __shfl_xor(ps, off, 64);
        pd += __shfl_xor(pd, off, 64);
    }
    if (l == 0) {
        asrc[n] = ps;
        adst[n] = pd;
    }
}

// ---------------- aggregation layer 1 (round-10): fp16 gathers, 8x unroll; fp16 out ----------------
__global__ __launch_bounds__(256) void k_agg1(const __half* __restrict__ h,
                                              const float* __restrict__ asrc,
                                              const float* __restrict__ adst,
                                              const int* __restrict__ rowptr,
                                              const int* __restrict__ csr_src,
                                              const float* __restrict__ b,
                                              __half* __restrict__ out) {
    int t = threadIdx.x;
    int n = blockIdx.x * 4 + (t >> 6);
    if (n >= NNODES) return;
    int l = t & 63;
    int head = l >> 4;
    int c0 = 2 * l;
    const __half2* hh = (const __half2*)h;

    float adsth = adst[n * 4 + head];
    float w = __expf(lrelu(asrc[n * 4 + head] + adsth));
    float2 hv = __half22float2(hh[(size_t)n * 64 + l]);
    float dsum = w;
    float a0 = w * hv.x;
    float a1 = w * hv.y;

    int beg = rowptr[n];
    int end = rowptr[n + 1];
    int p = beg;
    for (; p + 8 <= end; p += 8) {
        int s[8];
        #pragma unroll
        for (int j = 0; j < 8; ++j) s[j] = __builtin_amdgcn_readfirstlane(csr_src[p + j]);
        float ww[8];
        #pragma unroll
        for (int j = 0; j < 8; ++j) ww[j] = __expf(lrelu(asrc[(size_t)s[j] * 4 + head] + adsth));
        float2 hx[8];
        #pragma unroll
        for (int j = 0; j < 8; ++j) hx[j] = __half22float2(hh[(size_t)s[j] * 64 + l]);
        #pragma unroll
        for (int j = 0; j < 8; ++j) {
            dsum += ww[j];
            a0 = fmaf(ww[j], hx[j].x, a0);
            a1 = fmaf(ww[j], hx[j].y, a1);
        }
    }
    for (; p < end; ++p) {
        int s = __builtin_amdgcn_readfirstlane(csr_src[p]);
        float ws = __expf(lrelu(asrc[(size_t)s * 4 + head] + adsth));
        float2 hs = __half22float2(hh[(size_t)s * 64 + l]);
        dsum += ws;
        a0 = fmaf(ws, hs.x, a0);
        a1 = fmaf(ws, hs.y, a1);
    }
    float inv = 1.0f / dsum;
    float r0 = a0 * inv + b[c0];
    float r1 = a1 * inv + b[c0 + 1];
    r0 = r0 > 0.f ? r0 : __expf(r0) - 1.f;
    r1 = r1 > 0.f ? r1 : __expf(r1) - 1.f;
    ((__half2*)out)[(size_t)n * 64 + l] = __floats2half2_rn(r0, r1);
}

// ---------------- aggregation layer 2 (round-10, proven) ----------------
__global__ __launch_bounds__(256) void k_agg2(const __half* __restrict__ h,
                                              const float* __restrict__ asrc,
                                              const float* __restrict__ adst,
                                              const int* __restrict__ rowptr,
                                              const int* __restrict__ csr_src,
                                              const float* __restrict__ b,
                                              float* __restrict__ out) {
    int t = threadIdx.x;
    int n = blockIdx.x * 4 + (t >> 6);
    if (n >= NNODES) return;
    int l = t & 63;

    float adv = adst[n];
    float w = __expf(lrelu(asrc[n] + adv));
    float dsum = w;
    float acc = w * __half2float(h[(size_t)n * 64 + l]);

    int beg = rowptr[n];
    int end = rowptr[n + 1];
    int p = beg;
    for (; p + 8 <= end; p += 8) {
        int s[8];
        #pragma unroll
        for (int j = 0; j < 8; ++j) s[j] = __builtin_amdgcn_readfirstlane(csr_src[p + j]);
        float ww[8];
        #pragma unroll
        for (int j = 0; j < 8; ++j) ww[j] = __expf(lrelu(asrc[s[j]] + adv));
        float hx[8];
        #pragma unroll
        for (int j = 0; j < 8; ++j) hx[j] = __half2float(h[(size_t)s[j] * 64 + l]);
        #pragma unroll
        for (int j = 0; j < 8; ++j) {
            dsum += ww[j];
            acc = fmaf(ww[j], hx[j], acc);
        }
    }
    for (; p < end; ++p) {
        int s = __builtin_amdgcn_readfirstlane(csr_src[p]);
        float ws = __expf(lrelu(asrc[s] + adv));
        acc = fmaf(ws, __half2float(h[(size_t)s * 64 + l]), acc);
        dsum += ws;
    }
    out[(size_t)n * 64 + l] = acc / dsum + b[l];
}

extern "C" void kernel_launch(void* const* d_in, const int* in_sizes, int n_in,
                              void* d_out, int out_size, void* d_ws, size_t ws_size,
                              hipStream_t stream) {
    const float* x      = (const float*)d_in[0];
    const int*   ei     = (const int*)d_in[1];
    const float* W1     = (const float*)d_in[2];
    const float* a_src1 = (const float*)d_in[3];
    const float* a_dst1 = (const float*)d_in[4];
    const float* b1     = (const float*)d_in[5];
    const float* W2     = (const float*)d_in[6];
    const float* a_src2 = (const float*)d_in[7];
    const float* a_dst2 = (const float*)d_in[8];
    const float* b2     = (const float*)d_in[9];
    float* out = (float*)d_out;

    const int* src = ei;
    const int* dst = ei + NEDGES;

    char* ws = (char*)d_ws;
    size_t off = 0;
    auto alloc = [&](size_t bytes) {
        void* p = ws + off;
        off += (bytes + 255) & ~255ull;
        return p;
    };
    int* rowptr   = (int*)alloc((NNODES + 1) * sizeof(int));
    int* cursor   = (int*)alloc(NNODES * sizeof(int));
    int* csr_src  = (int*)alloc((size_t)NEDGES * sizeof(int));
    __half* h1h   = (__half*)alloc((size_t)NNODES * 128 * sizeof(__half));
    __half* eluh  = (__half*)alloc((size_t)NNODES * 128 * sizeof(__half));
    float* asrc1  = (float*)alloc((size_t)NNODES * 4 * sizeof(float));
    float* adst1  = (float*)alloc((size_t)NNODES * 4 * sizeof(float));
    __half* W1T   = (__half*)alloc(128 * 128 * sizeof(__half));
    __half* W2T   = (__half*)alloc(64 * 128 * sizeof(__half));
    int* bsum     = (int*)alloc(128 * sizeof(int));
    int* boff     = (int*)alloc(129 * sizeof(int));

    int nb = (NNODES + 1023) / 1024;  // 98

    hipMemsetAsync(cursor, 0, NNODES * sizeof(int), stream);
    k_cvtW1<<<64, 256, 0, stream>>>(W1, W1T);
    k_cvtW2<<<32, 256, 0, stream>>>(W2, W2T);
    k_degree<<<(NEDGES + 255) / 256, 256, 0, stream>>>(dst, cursor, NEDGES);
    k_scanA<<<nb, 1024, 0, stream>>>(cursor, rowptr, bsum, NNODES);
    k_scanB<<<1, 128, 0, stream>>>(bsum, boff, nb);
    k_scanC<<<nb, 1024, 0, stream>>>(rowptr, cursor, boff, NNODES, NEDGES);
    k_fill<<<NRANGES * 200, 256, 0, stream>>>(src, dst, cursor, csr_src, NEDGES);

    int gn = (NNODES + 3) / 4;
    int gb = (NNODES + 63) / 64;

    // layer 1
    k_gemm1<<<gb, 256, 0, stream>>>(x, W1T, h1h);
    k_alpha1<<<gn, 256, 0, stream>>>(h1h, a_src1, a_dst1, asrc1, adst1);
    k_agg1<<<gn, 256, 0, stream>>>(h1h, asrc1, adst1, rowptr, csr_src, b1, eluh);

    // layer 2 (h overlays h1h; asrc/adst reused)
    k_gemm2<<<gb, 256, 0, stream>>>(eluh, W2T, h1h);
    k_alpha2<<<gn, 256, 0, stream>>>(h1h, a_src2, a_dst2, asrc1, adst1);
    k_agg2<<<gn, 256, 0, stream>>>(h1h, asrc1, adst1, rowptr, csr_src, b2, out);
}